// Round 6
// baseline (312.450 us; speedup 1.0000x reference)
//
#include <hip/hip_runtime.h>
#include <stdint.h>

// GAT forward, MI355X. FP32 in/out; edge_index int32. N=50000, E=800000,
// HEADS=4, C=64 (HC=256).
// Pipeline (R14, 4 dispatches):
//   prep:   trans (W -> frag-major split bf16) + zero barrier counter.
//   csrall: ENTIRE CSR build in ONE kernel, 256 co-resident blocks, 4 custom
//           spin grid-barriers (atomicAdd arrive + __threadfence both sides;
//           R12/R13 proved spin-on-device-atomics ~us-cheap, vs cg
//           grid.sync ~110us). Phases: P1 LDS coarse hist (dst>>8) ->
//           cnt1[bucket][chunk] | P2 per-bucket-row 256-scan -> base1,
//           bsum[bucket]=total | P3 block0 scans bsum -> bucket bases |
//           P4 scatter packed (src|fine<<16) via LDS cursors -> part |
//           P5 per-bucket fine hist+scan -> deg/offs/csr_src. Zero global
//           atomics (R13: that was worth ~60us). Replaces 5 dispatches.
//   gemm:   H = x@W split-bf16 MFMA (3 terms, err ~2^-17), H bf16; att
//           logits fused in epilogue (wave=head). [unchanged]
//   gather: one wave per (node, head-pair); 2 ch/lane; 32-edge exp
//           amortization; XCD steering (FETCH 211->189MB). [unchanged]
// Softmax shift omitted: logits fp32-exact-ish (err ~1e-4), |e|<~12 ->
// exp<=1.6e5, fp32-safe; softmax is shift-invariant. Dominant output error =
// bf16 H storage (~0.016 absmax vs 0.0575 threshold, verified rounds 3-13).

using u16 = unsigned short;
typedef float f32x4 __attribute__((ext_vector_type(4)));
typedef __bf16 bf16x8 __attribute__((ext_vector_type(8)));
typedef u16 u16x8 __attribute__((ext_vector_type(8)));

#define NEG 0.2f
#define APAD 264   // 256 + 8 u16 pad: row stride 528 B -> 2-way LDS aliasing (free)
#define NBLK1 256  // csrall blocks (= chunk count); all co-resident on 256 CUs

__device__ __forceinline__ float bf2f(u16 u) {
    union { uint32_t i; float f; } v; v.i = ((uint32_t)u) << 16; return v.f;
}
__device__ __forceinline__ u16 f2bf(float f) {          // RNE
    union { float f; uint32_t i; } v; v.f = f;
    uint32_t r = v.i + 0x7FFFu + ((v.i >> 16) & 1u);
    return (u16)(r >> 16);
}
// trunc split: f ~= hi + lo with |err| ~ 2^-17 |f|
__device__ __forceinline__ void split2(float f, u16& h, u16& l) {
    union { float f; uint32_t i; } v; v.f = f;
    h = (u16)(v.i >> 16);
    float r = f - bf2f(h);
    union { float f; uint32_t i; } w; w.f = r;
    l = (u16)(w.i >> 16);
}
__device__ __forceinline__ float wexp(float e) {
    e = e >= 0.f ? e : NEG * e;
    return __expf(e);
}

// Spin grid barrier for co-resident grids. Release fence (wb L2) before
// arrive; acquire fence (inv L2) after target reached -> cross-XCD
// write->barrier->first-read is safe. Counter is monotonic per launch
// (targets 256,512,...); prep re-zeroes it each launch.
__device__ __forceinline__ void gridbar(unsigned* ctr, unsigned target) {
    __syncthreads();
    if (threadIdx.x == 0) {
        __threadfence();
        atomicAdd(ctr, 1u);
        while (atomicAdd(ctr, 0u) < target) __builtin_amdgcn_s_sleep(2);
        __threadfence();
    }
    __syncthreads();
}

// ---------------- prep: trans (W -> frag-major split bf16) + zero ctr ------
__global__ __launch_bounds__(256) void prep_kernel(
    const float* __restrict__ W, u16* __restrict__ Wfh, u16* __restrict__ Wfl,
    unsigned* __restrict__ ctr)
{
    const int tid = threadIdx.x;
    if (blockIdx.x == 0 && tid == 0) *ctr = 0u;
    // Wf[((kg*16+nb)*64+l)*8+j] =
    //   split(W[(kg*32+(l>>4)*8+j)*256 + nb*16+(l&15)])
    const int f = blockIdx.x * 4 + (tid >> 6);
    const int l = tid & 63;
    const int kg = f >> 4, nb = f & 15;
    const int n = nb * 16 + (l & 15);
    const int kb = kg * 32 + (l >> 4) * 8;
    u16x8 hv, lv;
#pragma unroll
    for (int j = 0; j < 8; j++) {
        u16 th, tl;
        split2(W[(size_t)(kb + j) * 256 + n], th, tl);
        hv[j] = th;
        lv[j] = tl;
    }
    *(u16x8*)(Wfh + ((size_t)f * 64 + l) * 8) = hv;
    *(u16x8*)(Wfl + ((size_t)f * 64 + l) * 8) = lv;
}

// ---------------- csrall: full CSR build, one dispatch ---------------------
__global__ __launch_bounds__(256) void csrall_kernel(
    const int* __restrict__ esrc, const int* __restrict__ edst,
    int* __restrict__ deg, int* __restrict__ offs,
    int* __restrict__ cnt1, int* __restrict__ base1, int* __restrict__ bsum,
    unsigned* __restrict__ ctr, uint32_t* __restrict__ part,
    int* __restrict__ csr_src, int E, int Nn, int nb1, int chunk)
{
    __shared__ int lds[256];
    __shared__ int wsum[4];
    const int tid = threadIdx.x, cb = blockIdx.x;
    const int ln = tid & 63, wv = tid >> 6;
    const int e0 = cb * chunk;
    const int e1 = (e0 + chunk < E) ? e0 + chunk : E;

    // ---- P1: LDS hist over coarse bucket (dst>>8) ----
    lds[tid] = 0;
    __syncthreads();
    for (int e = e0 + tid; e < e1; e += 256) {
        int i = edst[e];
        i = ((unsigned)i < (unsigned)Nn) ? i : 0;
        atomicAdd(&lds[i >> 8], 1);                  // LDS atomic
    }
    __syncthreads();
    if (tid < nb1) cnt1[tid * NBLK1 + cb] = lds[tid];
    gridbar(ctr, 1u * NBLK1);

    // ---- P2: blocks < nb1 scan their bucket-row (256 per-chunk counts) ----
    if (cb < nb1) {
        const int v = cnt1[cb * NBLK1 + tid];
        int s = v;
#pragma unroll
        for (int o = 1; o < 64; o <<= 1) {
            int u = __shfl_up(s, o, 64);
            if (ln >= o) s += u;
        }
        if (ln == 63) wsum[wv] = s;
        __syncthreads();
        int wpre = 0;
#pragma unroll
        for (int w2 = 0; w2 < 4; w2++) wpre += (w2 < wv) ? wsum[w2] : 0;
        base1[cb * NBLK1 + tid] = wpre + s - v;      // bucket-local exclusive
        if (tid == 255) bsum[cb] = wpre + s;         // bucket total
        __syncthreads();                             // wsum reused below
    }
    gridbar(ctr, 2u * NBLK1);

    // ---- P3: block 0 exclusive-scans bsum[0..nb1) -> bucket bases ----
    if (cb == 0) {
        const int v = (tid < nb1) ? bsum[tid] : 0;
        int s = v;
#pragma unroll
        for (int o = 1; o < 64; o <<= 1) {
            int u = __shfl_up(s, o, 64);
            if (ln >= o) s += u;
        }
        if (ln == 63) wsum[wv] = s;
        __syncthreads();
        int wpre = 0;
#pragma unroll
        for (int w2 = 0; w2 < 4; w2++) wpre += (w2 < wv) ? wsum[w2] : 0;
        if (tid < nb1) bsum[tid] = wpre + s - v;     // global bucket base
    }
    gridbar(ctr, 3u * NBLK1);

    // ---- P4: scatter packed records via LDS cursors ----
    if (tid < nb1) lds[tid] = bsum[tid] + base1[tid * NBLK1 + cb];
    __syncthreads();
    for (int e = e0 + tid; e < e1; e += 256) {
        int i = edst[e];
        i = ((unsigned)i < (unsigned)Nn) ? i : 0;
        int j = esrc[e];
        j = ((unsigned)j < (unsigned)Nn) ? j : 0;
        const int pos = atomicAdd(&lds[i >> 8], 1);  // LDS atomic
        part[pos] = (uint32_t)j | ((uint32_t)(i & 255) << 16);  // N<65536
    }
    gridbar(ctr, 4u * NBLK1);

    // ---- P5: per-bucket fine hist + scan -> deg/offs/csr_src ----
    if (cb < nb1) {
        const int bstart = bsum[cb];
        const int bend = (cb + 1 < nb1) ? bsum[cb + 1] : E;
        lds[tid] = 0;
        __syncthreads();
        for (int e = bstart + tid; e < bend; e += 256)
            atomicAdd(&lds[part[e] >> 16], 1);       // LDS atomic
        __syncthreads();
        const int cnt = lds[tid];
        int s = cnt;
#pragma unroll
        for (int o = 1; o < 64; o <<= 1) {
            int u = __shfl_up(s, o, 64);
            if (ln >= o) s += u;
        }
        __syncthreads();                             // wsum reuse (P2/P3)
        if (ln == 63) wsum[wv] = s;
        __syncthreads();
        int wpre = 0;
#pragma unroll
        for (int w2 = 0; w2 < 4; w2++) wpre += (w2 < wv) ? wsum[w2] : 0;
        const int ex = bstart + wpre + s - cnt;      // global exclusive
        const int node = (cb << 8) + tid;
        if (node < Nn) { deg[node] = cnt; offs[node] = ex; }
        __syncthreads();
        lds[tid] = ex;                               // reuse as cursors
        __syncthreads();
        for (int e = bstart + tid; e < bend; e += 256) {
            const uint32_t pr = part[e];
            const int pos = atomicAdd(&lds[pr >> 16], 1);   // LDS atomic
            csr_src[pos] = (int)(pr & 0xFFFFu);
        }
    }
}

// ---------------- GEMM: H = x @ W, LDS-staged A, frag-major B --------------
// att logits fused into the epilogue (wave w owns head w's columns).
__global__ __launch_bounds__(256, 2) void gemm_kernel(
    const float* __restrict__ X, const u16* __restrict__ Wfh,
    const u16* __restrict__ Wfl, const float* __restrict__ attS,
    const float* __restrict__ attD, u16* __restrict__ H,
    float* __restrict__ a_src, float* __restrict__ a_dst, int Nn)
{
    __shared__ u16 Ah[64 * APAD];
    __shared__ u16 Al[64 * APAD];
    const int tid = threadIdx.x, m0 = blockIdx.x * 64;
    const int wave = tid >> 6, lane = tid & 63;
    const int quad = lane >> 4, lr = lane & 15;

    // ---- stage X tile (64 rows x 256 cols) as split bf16 ----
#pragma unroll
    for (int i = 0; i < 16; i++) {
        const int f = i * 256 + tid;            // float4 index in tile
        const int row = f >> 6;                 // 64 float4 per row
        const int c4 = (f & 63) * 4;
        int grow = m0 + row;
        if (grow >= Nn) grow = Nn - 1;          // clamp; stores guarded
        const float4 v = *(const float4*)(X + (size_t)grow * 256 + c4);
        u16 h0, l0, h1, l1, h2, l2, h3, l3;
        split2(v.x, h0, l0); split2(v.y, h1, l1);
        split2(v.z, h2, l2); split2(v.w, h3, l3);
        uint2 hp, lp;
        hp.x = (uint32_t)h0 | ((uint32_t)h1 << 16);
        hp.y = (uint32_t)h2 | ((uint32_t)h3 << 16);
        lp.x = (uint32_t)l0 | ((uint32_t)l1 << 16);
        lp.y = (uint32_t)l2 | ((uint32_t)l3 << 16);
        *(uint2*)(Ah + row * APAD + c4) = hp;   // 8B aligned
        *(uint2*)(Al + row * APAD + c4) = lp;
    }
    __syncthreads();

    f32x4 acc[4][4] = {};                       // [mi][ni]
    bf16x8 bh[2][4], bl[2][4];                  // B double buffer

    // prologue: kg=0 B frags (frag id = kg*16 + wave*4 + ni)
#pragma unroll
    for (int ni = 0; ni < 4; ni++) {
        const size_t o = ((size_t)(wave * 4 + ni) * 64 + lane) * 8;
        bh[0][ni] = *(const bf16x8*)(Wfh + o);
        bl[0][ni] = *(const bf16x8*)(Wfl + o);
    }

#pragma unroll
    for (int kg = 0; kg < 8; kg++) {
        const int st = kg & 1, ns = st ^ 1;
        if (kg < 7) {                           // prefetch kg+1 B
#pragma unroll
            for (int ni = 0; ni < 4; ni++) {
                const size_t o = ((size_t)((kg + 1) * 16 + wave * 4 + ni) * 64 + lane) * 8;
                bh[ns][ni] = *(const bf16x8*)(Wfh + o);
                bl[ns][ni] = *(const bf16x8*)(Wfl + o);
            }
        }
        bf16x8 ah[4], al[4];
#pragma unroll
        for (int mi = 0; mi < 4; mi++) {
            const int o = (mi * 16 + lr) * APAD + kg * 32 + quad * 8;
            ah[mi] = *(const bf16x8*)(Ah + o);  // ds_read_b128
            al[mi] = *(const bf16x8*)(Al + o);
        }
#pragma unroll
        for (int ni = 0; ni < 4; ni++)
#pragma unroll
            for (int mi = 0; mi < 4; mi++) {
                acc[mi][ni] = __builtin_amdgcn_mfma_f32_16x16x32_bf16(
                    ah[mi], bh[st][ni], acc[mi][ni], 0, 0, 0);
                acc[mi][ni] = __builtin_amdgcn_mfma_f32_16x16x32_bf16(
                    ah[mi], bl[st][ni], acc[mi][ni], 0, 0, 0);
                acc[mi][ni] = __builtin_amdgcn_mfma_f32_16x16x32_bf16(
                    al[mi], bh[st][ni], acc[mi][ni], 0, 0, 0);
            }
    }

    // ---- epilogue 1: att logits from fp32 acc (wave = head) ----
    // a_src[row][wave] = sum_c acc(row, c) * attS[wave][c]; c = ni*16+lr.
    {
        float asv[4], adv[4];
#pragma unroll
        for (int ni = 0; ni < 4; ni++) {
            asv[ni] = attS[wave * 64 + ni * 16 + lr];
            adv[ni] = attD[wave * 64 + ni * 16 + lr];
        }
#pragma unroll
        for (int mi = 0; mi < 4; mi++)
#pragma unroll
            for (int r = 0; r < 4; r++) {
                float ps = 0.f, pd = 0.f;
#pragma unroll
                for (int ni = 0; ni < 4; ni++) {
                    ps += acc[mi][ni][r] * asv[ni];
                    pd += acc[mi][ni][r] * adv[ni];
                }
#pragma unroll
                for (int off = 8; off >= 1; off >>= 1) {
                    ps += __shfl_xor(ps, off, 16);   // reduce over lr group
                    pd += __shfl_xor(pd, off, 16);
                }
                if (lr == 0) {
                    const int row = m0 + mi * 16 + quad * 4 + r;
                    if (row < Nn) {
                        a_src[row * 4 + wave] = ps;
                        a_dst[row * 4 + wave] = pd;
                    }
                }
            }
    }

    // ---- epilogue 2: H store. C/D: col = lane&15 (lr), row = quad*4 + r ---
    const int n0 = wave * 64;
#pragma unroll
    for (int mi = 0; mi < 4; mi++)
#pragma unroll
        for (int ni = 0; ni < 4; ni++) {
            int col = n0 + ni * 16 + lr;
#pragma unroll
            for (int r = 0; r < 4; r++) {
                int row = m0 + mi * 16 + quad * 4 + r;
                if (row < Nn) H[(size_t)row * 256 + col] = f2bf(acc[mi][ni][r]);
            }
        }
}

// ---------------- gather: 1 wave/(node, head-pair), 2 ch/thread ------------
// blockIdx = g*8 + s; s&3 picks node sub-group, s>>2 picks head-pair ->
// blocks round-robin XCDs, so XCDs 0-3 serve hp=0 (bytes [0,256) of each H
// row) and XCDs 4-7 serve hp=1. 32-edge phase A: lane sub=lane&31 loads edge
// id + a_src + exp ONCE per 32 edges of its head; ids/weights broadcast via
// __shfl width 32. Rows processed in 16-deep sub-batches; dead tail slots
// clamp to the last valid edge's row (cache-hot, w=0).
__global__ __launch_bounds__(256) void gather_kernel(
    const u16* __restrict__ H, const int* __restrict__ offs,
    const int* __restrict__ deg, const int* __restrict__ csr_src,
    const float* __restrict__ a_src, const float* __restrict__ a_dst,
    const float* __restrict__ bias, const float* __restrict__ prelu,
    float* __restrict__ out, int Nn)
{
    const int wave = threadIdx.x >> 6, lane = threadIdx.x & 63;
    const int g = blockIdx.x >> 3, s = blockIdx.x & 7;
    const int hp = s >> 2;                        // head-pair -> XCD half
    const int node = ((g << 2) + (s & 3)) * 4 + wave;
    if (node >= Nn) return;
    const int hh = lane >> 5;
    const int head = (hp << 1) + hh;
    const int sub = lane & 31;
    const int ch = (head << 6) + sub * 2;         // 2 channels / lane

    const float adv = a_dst[node * 4 + head];
    const float ws = wexp(a_src[node * 4 + head] + adv);
    float acc0, acc1, sumw = 0.f;                 // sumw: own edges only
    {   // self loop
        const uint32_t hv = *(const uint32_t*)(H + (size_t)node * 256 + ch);
        acc0 = ws * bf2f((u16)hv);
        acc1 = ws * bf2f((u16)(hv >> 16));
    }
    const int d = deg[node];
    const int* __restrict__ cp = csr_src + offs[node];

    for (int k = 0; k < d; k += 32) {
        const int q = d - k;                      // edges left (>=1)
        const int es = (sub < q) ? sub : q - 1;
        const int jj = cp[k + es];                // in-range always
        float ww = wexp(a_src[jj * 4 + head] + adv);
        ww = (sub < q) ? ww : 0.f;
        sumw += ww;
        const int nh = (q > 16) ? 2 : 1;
        for (int half = 0; half < nh; half++) {
            const int hb = half << 4;
            uint32_t hv[16];
#pragma unroll
            for (int t = 0; t < 16; t++) {
                const int jt = __shfl(jj, hb + t, 32);
                hv[t] = *(const uint32_t*)(H + ((size_t)jt << 8) + ch);
            }
#pragma unroll
            for (int t = 0; t < 16; t++) {
                const float w = __shfl(ww, hb + t, 32);
                acc0 += w * bf2f((u16)hv[t]);
                acc1 += w * bf2f((u16)(hv[t] >> 16));
            }
        }
    }
    // total edge weight: reduce per-lane partials over the 32-lane head group
#pragma unroll
    for (int off = 16; off >= 1; off >>= 1)
        sumw += __shfl_xor(sumw, off, 32);

    const float inv = 1.f / (ws + sumw + 1e-16f);
    const float pa = prelu[0];
    float o0 = acc0 * inv + bias[ch];
    float o1 = acc1 * inv + bias[ch + 1];
    o0 = o0 >= 0.f ? o0 : pa * o0;
    o1 = o1 >= 0.f ? o1 : pa * o1;
    float2 ov; ov.x = o0; ov.y = o1;
    *(float2*)(out + (size_t)node * 256 + ch) = ov;
}

// ---------------------------------------------------------------------------
extern "C" void kernel_launch(void* const* d_in, const int* in_sizes, int n_in,
                              void* d_out, int out_size, void* d_ws, size_t ws_size,
                              hipStream_t stream)
{
    const float* X    = (const float*)d_in[0];
    const int*   EI   = (const int*)d_in[1];
    const float* W    = (const float*)d_in[2];
    const float* attS = (const float*)d_in[3];
    const float* attD = (const float*)d_in[4];
    const float* bias = (const float*)d_in[5];
    const float* pa   = (const float*)d_in[6];

    const int Nn = in_sizes[0] / 256;   // 50000
    const int E  = in_sizes[1] / 2;     // 800000
    const int* esrc = EI;
    const int* edst = EI + E;

    const int nb1   = (Nn + 255) >> 8;              // 196 coarse buckets
    const int chunk = (E + NBLK1 - 1) / NBLK1;      // 3125

    // workspace carve (~35 MB), all segments 16B-aligned
    char* p = (char*)d_ws;
    u16*      H       = (u16*)p;      p += (size_t)Nn * 256 * 2;
    float*    a_src   = (float*)p;    p += (size_t)Nn * 4 * 4;
    float*    a_dst   = (float*)p;    p += (size_t)Nn * 4 * 4;
    u16*      Wfh     = (u16*)p;      p += 256 * 256 * 2;
    u16*      Wfl     = (u16*)p;      p += 256 * 256 * 2;
    int*      deg     = (int*)p;      p += (size_t)Nn * 4;
    int*      offs    = (int*)p;      p += (size_t)Nn * 4;
    int*      cnt1    = (int*)p;      p += (size_t)256 * NBLK1 * 4;
    int*      base1   = (int*)p;      p += (size_t)256 * NBLK1 * 4;
    int*      bsum    = (int*)p;      p += 256 * 4;
    unsigned* ctr     = (unsigned*)p; p += 64 * 4;
    uint32_t* part    = (uint32_t*)p; p += (size_t)E * 4;
    int*      csr_src = (int*)p;      p += ((size_t)E + 16) * 4;

    prep_kernel<<<32, 256, 0, stream>>>(W, Wfh, Wfl, ctr);
    csrall_kernel<<<NBLK1, 256, 0, stream>>>(esrc, edst, deg, offs,
                                             cnt1, base1, bsum, ctr,
                                             part, csr_src, E, Nn, nb1, chunk);
    gemm_kernel<<<(Nn + 63) / 64, 256, 0, stream>>>(X, Wfh, Wfl, attS, attD,
                                                    H, a_src, a_dst, Nn);
    const int gblocks = ((Nn + 15) / 16) * 8;
    gather_kernel<<<gblocks, 256, 0, stream>>>(H, offs, deg, csr_src,
                                               a_src, a_dst, bias, pa,
                                               (float*)d_out, Nn);
}

// Round 7
// 237.207 us; speedup vs baseline: 1.3172x; 1.3172x over previous
//
#include <hip/hip_runtime.h>
#include <stdint.h>

// GAT forward, MI355X. FP32 in/out; edge_index int32. N=50000, E=800000,
// HEADS=4, C=64 (HC=256).
// Pipeline (R15, 4 dispatches, NO grid barriers — R11 cg sync ~110us/sync,
// R14 spin-barrier ~25us/sync both pathological; R15 uses redundant
// in-block recompute instead of sync):
//   prep:  trans (blocks 0-31) + coarse hist per chunk (all 256 blocks):
//          cnt1[chunk][bucket] (chunk-major -> later kernels re-derive any
//          prefix they need with coalesced 1KB reads).
//   mix:   blocks 0-255 = p1s: rebuild own base (column sums of cnt1 +
//          in-block 256-scan, ~1-2us) and scatter packed (src|fine<<16)
//          into part via LDS cursors. blocks 256+ = gemm (H = x@W split-bf16
//          MFMA, att logits fused; R15: H stored via LDS round-trip ->
//          8 coalesced dwordx4 stores/thread instead of 64 scalar u16).
//          p1s (~4us) hides completely under gemm (~65us).
//   p2:    per-bucket: rebuild bucket base (redundant column-sum + scan),
//          fine hist + scan -> deg/offs/csr_src. LDS atomics only.
//   gather: unchanged (71.7us, FETCH 189MB, XCD-steered head-pair split).
// Zero global atomics anywhere (R13: worth ~60us vs atomic hist/scatter).
// Softmax shift omitted: logits fp32-exact-ish (err ~1e-4), |e|<~12 ->
// exp<=1.6e5, fp32-safe; softmax is shift-invariant. Dominant output error =
// bf16 H storage (~0.016 absmax vs 0.0575 threshold, verified rounds 3-14).

using u16 = unsigned short;
typedef float f32x4 __attribute__((ext_vector_type(4)));
typedef __bf16 bf16x8 __attribute__((ext_vector_type(8)));
typedef u16 u16x8 __attribute__((ext_vector_type(8)));

#define NEG 0.2f
#define APAD 264   // 256 + 8 u16 pad: row stride 528 B -> 2-way LDS aliasing (free)
#define NBLK1 256  // partition chunks (= p1s blocks)

__device__ __forceinline__ float bf2f(u16 u) {
    union { uint32_t i; float f; } v; v.i = ((uint32_t)u) << 16; return v.f;
}
__device__ __forceinline__ u16 f2bf(float f) {          // RNE
    union { float f; uint32_t i; } v; v.f = f;
    uint32_t r = v.i + 0x7FFFu + ((v.i >> 16) & 1u);
    return (u16)(r >> 16);
}
// trunc split: f ~= hi + lo with |err| ~ 2^-17 |f|
__device__ __forceinline__ void split2(float f, u16& h, u16& l) {
    union { float f; uint32_t i; } v; v.f = f;
    h = (u16)(v.i >> 16);
    float r = f - bf2f(h);
    union { float f; uint32_t i; } w; w.f = r;
    l = (u16)(w.i >> 16);
}
__device__ __forceinline__ float wexp(float e) {
    e = e >= 0.f ? e : NEG * e;
    return __expf(e);
}

// ---------------- prep: trans (blocks 0-31) + coarse hist (all blocks) -----
__global__ __launch_bounds__(256) void prep_kernel(
    const float* __restrict__ W, u16* __restrict__ Wfh, u16* __restrict__ Wfl,
    const int* __restrict__ edst, int* __restrict__ cnt1,
    int E, int Nn, int chunk)
{
    __shared__ int h1[256];
    const int tid = threadIdx.x, cb = blockIdx.x;
    h1[tid] = 0;
    __syncthreads();
    const int e0 = cb * chunk;
    const int e1 = (e0 + chunk < E) ? e0 + chunk : E;
    for (int e = e0 + tid; e < e1; e += 256) {
        int i = edst[e];
        i = ((unsigned)i < (unsigned)Nn) ? i : 0;
        atomicAdd(&h1[i >> 8], 1);                   // LDS atomic
    }
    __syncthreads();
    cnt1[cb * 256 + tid] = h1[tid];                  // chunk-major, coalesced

    if (cb < 32) {
        // Wf[((kg*16+nb)*64+l)*8+j] =
        //   split(W[(kg*32+(l>>4)*8+j)*256 + nb*16+(l&15)])
        const int f = cb * 4 + (tid >> 6);
        const int l = tid & 63;
        const int kg = f >> 4, nb = f & 15;
        const int n = nb * 16 + (l & 15);
        const int kb = kg * 32 + (l >> 4) * 8;
        u16x8 hv, lv;
#pragma unroll
        for (int j = 0; j < 8; j++) {
            u16 th, tl;
            split2(W[(size_t)(kb + j) * 256 + n], th, tl);
            hv[j] = th;
            lv[j] = tl;
        }
        *(u16x8*)(Wfh + ((size_t)f * 64 + l) * 8) = hv;
        *(u16x8*)(Wfl + ((size_t)f * 64 + l) * 8) = lv;
    }
}

// ---------------- mix: blocks 0-255 p1s scatter; blocks 256+ gemm ----------
__global__ __launch_bounds__(256, 2) void mix_kernel(
    const float* __restrict__ X, const u16* __restrict__ Wfh,
    const u16* __restrict__ Wfl, const float* __restrict__ attS,
    const float* __restrict__ attD, u16* __restrict__ H,
    float* __restrict__ a_src, float* __restrict__ a_dst,
    const int* __restrict__ esrc, const int* __restrict__ edst,
    const int* __restrict__ cnt1, uint32_t* __restrict__ part,
    int E, int Nn, int chunk)
{
    __shared__ u16 Ah[64 * APAD];
    __shared__ u16 Al[64 * APAD];
    __shared__ int cur[256];
    __shared__ int wsum[4];
    const int tid = threadIdx.x;
    const int ln = tid & 63, wv = tid >> 6;

    if (blockIdx.x < NBLK1) {
        // ============== p1s: scatter chunk cb into bucket partitions =======
        const int cb = blockIdx.x;
        // rebuild base: thread tid owns bucket tid.
        int pre = 0, tot = 0;
        for (int c = 0; c < NBLK1; c++) {            // coalesced 1KB reads
            const int v = cnt1[c * 256 + tid];
            tot += v;
            pre += (c < cb) ? v : 0;
        }
        int s = tot;
#pragma unroll
        for (int o = 1; o < 64; o <<= 1) {
            int u = __shfl_up(s, o, 64);
            if (ln >= o) s += u;
        }
        if (ln == 63) wsum[wv] = s;
        __syncthreads();
        int wpre = 0;
#pragma unroll
        for (int w2 = 0; w2 < 4; w2++) wpre += (w2 < wv) ? wsum[w2] : 0;
        cur[tid] = (wpre + s - tot) + pre;           // bucket base + chunk pre
        __syncthreads();
        const int e0 = cb * chunk;
        const int e1 = (e0 + chunk < E) ? e0 + chunk : E;
        for (int e = e0 + tid; e < e1; e += 256) {
            int i = edst[e];
            i = ((unsigned)i < (unsigned)Nn) ? i : 0;
            int j = esrc[e];
            j = ((unsigned)j < (unsigned)Nn) ? j : 0;
            const int pos = atomicAdd(&cur[i >> 8], 1);    // LDS atomic
            part[pos] = (uint32_t)j | ((uint32_t)(i & 255) << 16); // N<65536
        }
        return;
    }

    // ================== gemm block =========================================
    const int m0 = (blockIdx.x - NBLK1) * 64;
    const int wave = tid >> 6, lane = tid & 63;
    const int quad = lane >> 4, lr = lane & 15;

    // ---- stage X tile (64 rows x 256 cols) as split bf16 ----
#pragma unroll
    for (int i = 0; i < 16; i++) {
        const int f = i * 256 + tid;            // float4 index in tile
        const int row = f >> 6;                 // 64 float4 per row
        const int c4 = (f & 63) * 4;
        int grow = m0 + row;
        if (grow >= Nn) grow = Nn - 1;          // clamp; stores guarded
        const float4 v = *(const float4*)(X + (size_t)grow * 256 + c4);
        u16 h0, l0, h1, l1, h2, l2, h3, l3;
        split2(v.x, h0, l0); split2(v.y, h1, l1);
        split2(v.z, h2, l2); split2(v.w, h3, l3);
        uint2 hp, lp;
        hp.x = (uint32_t)h0 | ((uint32_t)h1 << 16);
        hp.y = (uint32_t)h2 | ((uint32_t)h3 << 16);
        lp.x = (uint32_t)l0 | ((uint32_t)l1 << 16);
        lp.y = (uint32_t)l2 | ((uint32_t)l3 << 16);
        *(uint2*)(Ah + row * APAD + c4) = hp;   // 8B aligned
        *(uint2*)(Al + row * APAD + c4) = lp;
    }
    __syncthreads();

    f32x4 acc[4][4] = {};                       // [mi][ni]
    bf16x8 bh[2][4], bl[2][4];                  // B double buffer

    // prologue: kg=0 B frags (frag id = kg*16 + wave*4 + ni)
#pragma unroll
    for (int ni = 0; ni < 4; ni++) {
        const size_t o = ((size_t)(wave * 4 + ni) * 64 + lane) * 8;
        bh[0][ni] = *(const bf16x8*)(Wfh + o);
        bl[0][ni] = *(const bf16x8*)(Wfl + o);
    }

#pragma unroll
    for (int kg = 0; kg < 8; kg++) {
        const int st = kg & 1, ns = st ^ 1;
        if (kg < 7) {                           // prefetch kg+1 B
#pragma unroll
            for (int ni = 0; ni < 4; ni++) {
                const size_t o = ((size_t)((kg + 1) * 16 + wave * 4 + ni) * 64 + lane) * 8;
                bh[ns][ni] = *(const bf16x8*)(Wfh + o);
                bl[ns][ni] = *(const bf16x8*)(Wfl + o);
            }
        }
        bf16x8 ah[4], al[4];
#pragma unroll
        for (int mi = 0; mi < 4; mi++) {
            const int o = (mi * 16 + lr) * APAD + kg * 32 + quad * 8;
            ah[mi] = *(const bf16x8*)(Ah + o);  // ds_read_b128
            al[mi] = *(const bf16x8*)(Al + o);
        }
#pragma unroll
        for (int ni = 0; ni < 4; ni++)
#pragma unroll
            for (int mi = 0; mi < 4; mi++) {
                acc[mi][ni] = __builtin_amdgcn_mfma_f32_16x16x32_bf16(
                    ah[mi], bh[st][ni], acc[mi][ni], 0, 0, 0);
                acc[mi][ni] = __builtin_amdgcn_mfma_f32_16x16x32_bf16(
                    ah[mi], bl[st][ni], acc[mi][ni], 0, 0, 0);
                acc[mi][ni] = __builtin_amdgcn_mfma_f32_16x16x32_bf16(
                    al[mi], bh[st][ni], acc[mi][ni], 0, 0, 0);
            }
    }

    // ---- epilogue 1: att logits from fp32 acc (wave = head); reg/shfl only
    {
        float asv[4], adv[4];
#pragma unroll
        for (int ni = 0; ni < 4; ni++) {
            asv[ni] = attS[wave * 64 + ni * 16 + lr];
            adv[ni] = attD[wave * 64 + ni * 16 + lr];
        }
#pragma unroll
        for (int mi = 0; mi < 4; mi++)
#pragma unroll
            for (int r = 0; r < 4; r++) {
                float ps = 0.f, pd = 0.f;
#pragma unroll
                for (int ni = 0; ni < 4; ni++) {
                    ps += acc[mi][ni][r] * asv[ni];
                    pd += acc[mi][ni][r] * adv[ni];
                }
#pragma unroll
                for (int off = 8; off >= 1; off >>= 1) {
                    ps += __shfl_xor(ps, off, 16);   // reduce over lr group
                    pd += __shfl_xor(pd, off, 16);
                }
                if (lr == 0) {
                    const int row = m0 + mi * 16 + quad * 4 + r;
                    if (row < Nn) {
                        a_src[row * 4 + wave] = ps;
                        a_dst[row * 4 + wave] = pd;
                    }
                }
            }
    }

    // ---- epilogue 2: H store via LDS round-trip (coalesced dwordx4) ----
    __syncthreads();                            // main-loop Ah reads done
    const int n0 = wave * 64;
#pragma unroll
    for (int mi = 0; mi < 4; mi++)
#pragma unroll
        for (int ni = 0; ni < 4; ni++) {
            const int col = n0 + ni * 16 + lr;
#pragma unroll
            for (int r = 0; r < 4; r++)
                Ah[(mi * 16 + quad * 4 + r) * APAD + col] = f2bf(acc[mi][ni][r]);
        }
    __syncthreads();
#pragma unroll
    for (int swp = 0; swp < 8; swp++) {
        const int idx = swp * 256 + tid;        // 2048 chunks of 16B
        const int row = idx >> 5;               // 32 chunks per 512B row
        const int c16 = idx & 31;
        const int grow = m0 + row;
        if (grow < Nn)
            *(u16x8*)(H + (size_t)grow * 256 + c16 * 8) =
                *(const u16x8*)(Ah + row * APAD + c16 * 8);
    }
}

// ---------------- p2: per-bucket fine hist + scan -> deg/offs/csr_src ------
__global__ __launch_bounds__(256) void p2_kernel(
    const uint32_t* __restrict__ part, const int* __restrict__ cnt1,
    int* __restrict__ deg, int* __restrict__ offs, int* __restrict__ csr_src,
    int E, int Nn, int nb1)
{
    __shared__ int lds[256];
    __shared__ int wsum[4];
    __shared__ int sbd[2];
    const int b = blockIdx.x, tid = threadIdx.x;
    const int ln = tid & 63, wv = tid >> 6;

    // rebuild bucket bases: thread tid owns bucket tid
    int tot = 0;
    for (int c = 0; c < NBLK1; c++) tot += cnt1[c * 256 + tid];
    int s = tot;
#pragma unroll
    for (int o = 1; o < 64; o <<= 1) {
        int u = __shfl_up(s, o, 64);
        if (ln >= o) s += u;
    }
    if (ln == 63) wsum[wv] = s;
    __syncthreads();
    int wpre = 0;
#pragma unroll
    for (int w2 = 0; w2 < 4; w2++) wpre += (w2 < wv) ? wsum[w2] : 0;
    if (tid == b) { sbd[0] = wpre + s - tot; sbd[1] = wpre + s; }
    __syncthreads();
    const int bstart = sbd[0], bend = sbd[1];

    // fine hist (dst&255)
    lds[tid] = 0;
    __syncthreads();
    for (int e = bstart + tid; e < bend; e += 256)
        atomicAdd(&lds[part[e] >> 16], 1);           // LDS atomic
    __syncthreads();
    const int cnt = lds[tid];
    int s2 = cnt;
#pragma unroll
    for (int o = 1; o < 64; o <<= 1) {
        int u = __shfl_up(s2, o, 64);
        if (ln >= o) s2 += u;
    }
    if (ln == 63) wsum[wv] = s2;
    __syncthreads();
    int wpre2 = 0;
#pragma unroll
    for (int w2 = 0; w2 < 4; w2++) wpre2 += (w2 < wv) ? wsum[w2] : 0;
    const int ex = bstart + wpre2 + s2 - cnt;        // global exclusive
    const int node = (b << 8) + tid;
    if (node < Nn) { deg[node] = cnt; offs[node] = ex; }
    __syncthreads();
    lds[tid] = ex;                                   // reuse as cursors
    __syncthreads();
    for (int e = bstart + tid; e < bend; e += 256) {
        const uint32_t pr = part[e];
        const int pos = atomicAdd(&lds[pr >> 16], 1);       // LDS atomic
        csr_src[pos] = (int)(pr & 0xFFFFu);
    }
}

// ---------------- gather: 1 wave/(node, head-pair), 2 ch/thread ------------
// blockIdx = g*8 + s; s&3 picks node sub-group, s>>2 picks head-pair ->
// blocks round-robin XCDs, so XCDs 0-3 serve hp=0 (bytes [0,256) of each H
// row) and XCDs 4-7 serve hp=1. 32-edge phase A: lane sub=lane&31 loads edge
// id + a_src + exp ONCE per 32 edges of its head; ids/weights broadcast via
// __shfl width 32. Rows processed in 16-deep sub-batches; dead tail slots
// clamp to the last valid edge's row (cache-hot, w=0).
__global__ __launch_bounds__(256) void gather_kernel(
    const u16* __restrict__ H, const int* __restrict__ offs,
    const int* __restrict__ deg, const int* __restrict__ csr_src,
    const float* __restrict__ a_src, const float* __restrict__ a_dst,
    const float* __restrict__ bias, const float* __restrict__ prelu,
    float* __restrict__ out, int Nn)
{
    const int wave = threadIdx.x >> 6, lane = threadIdx.x & 63;
    const int g = blockIdx.x >> 3, s = blockIdx.x & 7;
    const int hp = s >> 2;                        // head-pair -> XCD half
    const int node = ((g << 2) + (s & 3)) * 4 + wave;
    if (node >= Nn) return;
    const int hh = lane >> 5;
    const int head = (hp << 1) + hh;
    const int sub = lane & 31;
    const int ch = (head << 6) + sub * 2;         // 2 channels / lane

    const float adv = a_dst[node * 4 + head];
    const float ws = wexp(a_src[node * 4 + head] + adv);
    float acc0, acc1, sumw = 0.f;                 // sumw: own edges only
    {   // self loop
        const uint32_t hv = *(const uint32_t*)(H + (size_t)node * 256 + ch);
        acc0 = ws * bf2f((u16)hv);
        acc1 = ws * bf2f((u16)(hv >> 16));
    }
    const int d = deg[node];
    const int* __restrict__ cp = csr_src + offs[node];

    for (int k = 0; k < d; k += 32) {
        const int q = d - k;                      // edges left (>=1)
        const int es = (sub < q) ? sub : q - 1;
        const int jj = cp[k + es];                // in-range always
        float ww = wexp(a_src[jj * 4 + head] + adv);
        ww = (sub < q) ? ww : 0.f;
        sumw += ww;
        const int nh = (q > 16) ? 2 : 1;
        for (int half = 0; half < nh; half++) {
            const int hb = half << 4;
            uint32_t hv[16];
#pragma unroll
            for (int t = 0; t < 16; t++) {
                const int jt = __shfl(jj, hb + t, 32);
                hv[t] = *(const uint32_t*)(H + ((size_t)jt << 8) + ch);
            }
#pragma unroll
            for (int t = 0; t < 16; t++) {
                const float w = __shfl(ww, hb + t, 32);
                acc0 += w * bf2f((u16)hv[t]);
                acc1 += w * bf2f((u16)(hv[t] >> 16));
            }
        }
    }
    // total edge weight: reduce per-lane partials over the 32-lane head group
#pragma unroll
    for (int off = 16; off >= 1; off >>= 1)
        sumw += __shfl_xor(sumw, off, 32);

    const float inv = 1.f / (ws + sumw + 1e-16f);
    const float pa = prelu[0];
    float o0 = acc0 * inv + bias[ch];
    float o1 = acc1 * inv + bias[ch + 1];
    o0 = o0 >= 0.f ? o0 : pa * o0;
    o1 = o1 >= 0.f ? o1 : pa * o1;
    float2 ov; ov.x = o0; ov.y = o1;
    *(float2*)(out + (size_t)node * 256 + ch) = ov;
}

// ---------------------------------------------------------------------------
extern "C" void kernel_launch(void* const* d_in, const int* in_sizes, int n_in,
                              void* d_out, int out_size, void* d_ws, size_t ws_size,
                              hipStream_t stream)
{
    const float* X    = (const float*)d_in[0];
    const int*   EI   = (const int*)d_in[1];
    const float* W    = (const float*)d_in[2];
    const float* attS = (const float*)d_in[3];
    const float* attD = (const float*)d_in[4];
    const float* bias = (const float*)d_in[5];
    const float* pa   = (const float*)d_in[6];

    const int Nn = in_sizes[0] / 256;   // 50000
    const int E  = in_sizes[1] / 2;     // 800000
    const int* esrc = EI;
    const int* edst = EI + E;

    const int nb1   = (Nn + 255) >> 8;              // 196 coarse buckets
    const int chunk = (E + NBLK1 - 1) / NBLK1;      // 3125

    // workspace carve (~34 MB), all segments 16B-aligned
    char* p = (char*)d_ws;
    u16*      H       = (u16*)p;      p += (size_t)Nn * 256 * 2;
    float*    a_src   = (float*)p;    p += (size_t)Nn * 4 * 4;
    float*    a_dst   = (float*)p;    p += (size_t)Nn * 4 * 4;
    u16*      Wfh     = (u16*)p;      p += 256 * 256 * 2;
    u16*      Wfl     = (u16*)p;      p += 256 * 256 * 2;
    int*      deg     = (int*)p;      p += (size_t)Nn * 4;
    int*      offs    = (int*)p;      p += (size_t)Nn * 4;
    int*      cnt1    = (int*)p;      p += (size_t)NBLK1 * 256 * 4;
    uint32_t* part    = (uint32_t*)p; p += (size_t)E * 4;
    int*      csr_src = (int*)p;      p += ((size_t)E + 16) * 4;

    prep_kernel<<<NBLK1, 256, 0, stream>>>(W, Wfh, Wfl, edst, cnt1,
                                           E, Nn, chunk);
    const int gemmBlocks = (Nn + 63) / 64;
    mix_kernel<<<NBLK1 + gemmBlocks, 256, 0, stream>>>(
        X, Wfh, Wfl, attS, attD, H, a_src, a_dst,
        esrc, edst, cnt1, part, E, Nn, chunk);
    p2_kernel<<<nb1, 256, 0, stream>>>(part, cnt1, deg, offs, csr_src,
                                       E, Nn, nb1);
    const int gblocks = ((Nn + 15) / 16) * 8;
    gather_kernel<<<gblocks, 256, 0, stream>>>(H, offs, deg, csr_src,
                                               a_src, a_dst, bias, pa,
                                               (float*)d_out, Nn);
}